// Round 6
// baseline (380.727 us; speedup 1.0000x reference)
//
#include <hip/hip_runtime.h>
#include <math.h>

#define C 256
#define NN 4096
#define SDIM 64                  // S = number of sentences (fixed 64)
#define T_INV 10.0f
#define NEG_IOU_TH 0.5f
#define SG 32                    // sentences per q-block
#define QTILE 256                // flats per q-block (1 per thread)
#define QTILES (NN / QTILE)      // 16

__device__ __forceinline__ float wave_reduce_sum(float v) {
    #pragma unroll
    for (int off = 32; off > 0; off >>= 1) v += __shfl_xor(v, off, 64);
    return v;
}

// --- prep: normalize sents -> sfT (c-major, s stride-1); block 0 builds
//     scatter maps (parallel prefix per thread) and zeroes denomq+counter. --
__global__ void k_prep(const float* __restrict__ sents,
                       const int* __restrict__ num_sentences,
                       const int* __restrict__ num_targets,
                       int B, int S, int M,
                       float* __restrict__ sfT, int* __restrict__ b2s,
                       int* __restrict__ s2b, int* __restrict__ m2s,
                       float* __restrict__ denomq, int* __restrict__ counter) {
    __shared__ float red[4];
    int s = blockIdx.x, tid = threadIdx.x;
    float v = sents[(size_t)s * C + tid];
    float ssq = wave_reduce_sum(v * v);
    int lane = tid & 63, wave = tid >> 6;
    if (lane == 0) red[wave] = ssq;
    __syncthreads();
    float tot = red[0] + red[1] + red[2] + red[3];
    sfT[(size_t)tid * S + s] = v * (1.0f / fmaxf(sqrtf(tot), 1e-12f));

    if (blockIdx.x == 0) {
        if (tid < S) denomq[tid] = 0.f;
        if (tid == 0) *counter = 0;
        if (tid < B) {                       // b2s + s2b, one thread per batch
            int acc = 0;
            for (int i = 0; i < tid; ++i) acc += num_sentences[i];
            b2s[tid] = acc;
            int nsb = num_sentences[tid];
            for (int k = 0; k < nsb; ++k) s2b[acc + k] = tid;
        }
        if (tid >= 64 && tid < 64 + S) {     // m2s, one thread per sentence
            int si = tid - 64;
            int acc = 0;
            for (int i = 0; i < si; ++i) acc += num_targets[i];
            int nt = num_targets[si];
            for (int k = 0; k < nt; ++k) m2s[acc + k] = si;
        }
    }
}

// --- main: blocks [0,M) = topk/inter-video (latency-heavy, start first);
//     blocks [M, M+512) = inter-query GEMM+exp.
//     Q-part: 1 flat/thread, 32 sentences/block, sentence operand via
//     wave-uniform loads (SGPR), unroll 16 for 16 vf loads in flight.
//     Last-finishing block computes the final loss. ----------------------
__global__ void __launch_bounds__(256)
k_main(const float* __restrict__ vf, const float* __restrict__ iou2d,
       const float* __restrict__ iou2ds, const int* __restrict__ num_sentences,
       const float* __restrict__ sfT, const int* __restrict__ b2s,
       const int* __restrict__ m2s,
       float* __restrict__ pos, float* __restrict__ negiv,
       float* __restrict__ denomq, int* __restrict__ counter,
       float* __restrict__ out, int S, int B, int M, int nq, int ntot) {
    __shared__ float red[4];
    __shared__ int   sidx[4];
    __shared__ float dw[4][SDIM];
    __shared__ int   bestflat;
    __shared__ int   amlast;
    __shared__ float tv[C];        // m-part only
    __shared__ float sc4[256];     // m-part only

    int bid = blockIdx.x, tid = threadIdx.x;
    int lane = tid & 63, wave = tid >> 6;

    if (bid >= M) {
        // ================= inter-query part =================
        int qb   = bid - M;              // [0, 512)
        int tile = qb & (QTILES - 1);    // 16 flat-tiles
        int rem  = qb >> 4;
        int b    = rem & 15;             // 16 videos
        int g    = rem >> 4;             // 2 sentence-groups of 32
        int sb = b2s[b];
        int ns = num_sentences[b];

        int flat = tile * QTILE + tid;   // this thread's proposal
        const float* vp = vf + (size_t)sb * C * NN + flat;
        // wave-uniform sentence pointer: float4 chunks of this group's 32 s
        const float4* sq = (const float4*)sfT + (size_t)g * 8;

        float acc[SG];                   // fully-unrolled -> stays in VGPRs
        #pragma unroll
        for (int s = 0; s < SG; ++s) acc[s] = 0.f;
        float ssq = 0.f;

        #pragma unroll 16
        for (int c = 0; c < C; ++c) {
            float v = vp[(size_t)c * NN];          // coalesced vector load
            ssq += v * v;
            const float4* sqc = sq + (size_t)c * (SDIM / 4);
            #pragma unroll
            for (int k = 0; k < SG / 4; ++k) {
                float4 q4 = sqc[k];                // uniform -> s_load
                acc[k * 4 + 0] += q4.x * v;
                acc[k * 4 + 1] += q4.y * v;
                acc[k * 4 + 2] += q4.z * v;
                acc[k * 4 + 3] += q4.w * v;
            }
        }

        int r = flat >> 6, cc = flat & 63;
        bool valid = (cc >= r);          // triu(mask2d)
        float scale = (1.0f / fmaxf(sqrtf(ssq), 1e-12f)) * T_INV;

        // own-batch positives are excluded from the denominator
        unsigned long long excl = 0ull;
        for (int i = 0; i < ns; ++i)
            if (iou2d[(size_t)(sb + i) * NN + flat] > NEG_IOU_TH)
                excl |= (1ull << (sb + i));
        if (!valid) excl = ~0ull;        // invalid flat contributes nothing

        unsigned mask32 = (unsigned)(excl >> (g * 32));
        #pragma unroll
        for (int i = 0; i < SG; ++i)
            acc[i] = ((mask32 >> i) & 1u) ? 0.f : expf(acc[i] * scale);

        // log-transpose reduce within each 32-lane half:
        // after this, lane l holds sum over its half's lanes of acc[l&31]
        #pragma unroll
        for (int off = 16; off >= 1; off >>= 1) {
            int bsel = lane & off;
            #pragma unroll
            for (int i = 0; i < off; ++i) {
                float keep = bsel ? acc[off + i] : acc[i];
                float send = bsel ? acc[i] : acc[off + i];
                acc[i] = keep + __shfl_xor(send, off, 64);
            }
        }
        float tot_s = acc[0] + __shfl_xor(acc[0], 32, 64);  // combine halves
        if (lane < 32) dw[wave][lane] = tot_s;   // s = g*32 + lane
        __syncthreads();
        if (tid < 32)
            atomicAdd(&denomq[g * 32 + tid],
                      dw[0][tid] + dw[1][tid] + dw[2][tid] + dw[3][tid]);
    } else {
        // ================= topk / inter-video part =================
        int m = bid;
        int s_m = m2s[m];

        float bv = -1e30f; int bi = NN;
        #pragma unroll
        for (int j = 0; j < NN / 256; ++j) {
            int flat = tid + j * 256;
            int rr = flat >> 6, cc = flat & 63;
            if (cc >= rr) {
                float val = iou2ds[(size_t)m * NN + flat];
                if (val > bv || (val == bv && flat < bi)) { bv = val; bi = flat; }
            }
        }
        #pragma unroll
        for (int off = 32; off > 0; off >>= 1) {
            float ov = __shfl_xor(bv, off, 64);
            int   oi = __shfl_xor(bi, off, 64);
            if (ov > bv || (ov == bv && oi < bi)) { bv = ov; bi = oi; }
        }
        if (lane == 0) { red[wave] = bv; sidx[wave] = bi; }
        __syncthreads();
        if (tid == 0) {
            float v0 = red[0]; int i0 = sidx[0];
            for (int w = 1; w < 4; ++w)
                if (red[w] > v0 || (red[w] == v0 && sidx[w] < i0)) { v0 = red[w]; i0 = sidx[w]; }
            bestflat = i0;
        }
        __syncthreads();
        int flat = bestflat;

        float v = vf[((size_t)s_m * C + tid) * NN + flat];
        float ssq = wave_reduce_sum(v * v);
        if (lane == 0) red[wave] = ssq;
        __syncthreads();
        float tot = red[0] + red[1] + red[2] + red[3];
        tv[tid] = v * (1.0f / fmaxf(sqrtf(tot), 1e-12f));
        __syncthreads();

        {
            int s = tid & 63, cg = tid >> 6;
            float d = 0.f;
            for (int j = 0; j < 64; ++j) {
                int c2 = cg * 64 + j;
                d += tv[c2] * sfT[(size_t)c2 * S + s];
            }
            sc4[cg * 64 + s] = d;
        }
        __syncthreads();
        if (tid < 64) {
            float d = sc4[tid] + sc4[64 + tid] + sc4[128 + tid] + sc4[192 + tid];
            if (tid == s_m) atomicExch(&pos[m], d);   // device-scope publish
            float e = (tid == s_m) ? 0.f : expf(d * T_INV);
            e = wave_reduce_sum(e);
            if (tid == 0) atomicExch(&negiv[m], e);   // device-scope publish
        }
    }

    // ---- completion tail: last block to finish computes the final loss ----
    __syncthreads();   // drains this block's outstanding memory ops
    if (tid == 0) {
        __threadfence();
        int old = atomicAdd(counter, 1);
        amlast = (old == ntot - 1) ? 1 : 0;
    }
    __syncthreads();
    if (!amlast) return;

    __threadfence();
    float val = 0.f;
    for (int m = tid; m < M; m += 256) {
        int s = m2s[m];
        float pl  = atomicAdd(&pos[m], 0.f) * T_INV;       // coherent reads
        float niv = atomicAdd(&negiv[m], 0.f);
        float dq  = atomicAdd(&denomq[s], 0.f);
        float pe = expf(pl);
        val += -(pl - logf(pe + niv)) + -(pl - logf(pe + dq));
    }
    val = wave_reduce_sum(val);
    if (lane == 0) dw[0][wave] = val;
    __syncthreads();
    if (tid == 0) out[0] = (dw[0][0] + dw[0][1] + dw[0][2] + dw[0][3]) / (float)M;
}

extern "C" void kernel_launch(void* const* d_in, const int* in_sizes, int n_in,
                              void* d_out, int out_size, void* d_ws, size_t ws_size,
                              hipStream_t stream) {
    const float* video_feats   = (const float*)d_in[0];
    const float* sents_feats   = (const float*)d_in[1];
    const float* iou2d         = (const float*)d_in[2];
    const float* iou2ds        = (const float*)d_in[3];
    const int*   num_sentences = (const int*)d_in[4];
    const int*   num_targets   = (const int*)d_in[5];
    // d_in[6] = mask2d: statically triu(ones(64,64)); computed as cc>=r in-kernel.

    const int S = in_sizes[2] / NN;   // 64
    const int B = in_sizes[4];        // 16
    const int M = in_sizes[3] / NN;   // 128

    float* sfT    = (float*)d_ws;              // C*S
    float* pos    = sfT + (size_t)C * 64;
    float* negiv  = pos + M;
    float* denomq = negiv + M;
    int*   b2s    = (int*)(denomq + S);
    int*   s2b    = b2s + B;
    int*   m2s    = s2b + S;
    int*   counter = m2s + M;

    const int nq   = QTILES * B * (SDIM / SG);   // 16*16*2 = 512 q-blocks
    const int ntot = M + nq;                     // 640

    k_prep<<<S, C, 0, stream>>>(sents_feats, num_sentences, num_targets,
                                B, S, M, sfT, b2s, s2b, m2s, denomq, counter);
    k_main<<<ntot, 256, 0, stream>>>(video_feats, iou2d, iou2ds, num_sentences,
                                     sfT, b2s, m2s, pos, negiv, denomq, counter,
                                     (float*)d_out, S, B, M, nq, ntot);
}

// Round 7
// 368.369 us; speedup vs baseline: 1.0335x; 1.0335x over previous
//
#include <hip/hip_runtime.h>
#include <math.h>

#define C 256
#define NN 4096
#define SDIM 64                  // S = number of sentences (fixed 64)
#define T_INV 10.0f
#define NEG_IOU_TH 0.5f
#define SG 32                    // sentences per q-block
#define QTILE 256                // flats per q-block (1 per thread)
#define QTILES (NN / QTILE)      // 16

__device__ __forceinline__ float wave_reduce_sum(float v) {
    #pragma unroll
    for (int off = 32; off > 0; off >>= 1) v += __shfl_xor(v, off, 64);
    return v;
}

// --- prep: normalize sents -> sfT (c-major, s stride-1); block 0 builds
//     scatter maps (parallel prefix per thread) and zeroes denomq+counter. --
__global__ void k_prep(const float* __restrict__ sents,
                       const int* __restrict__ num_sentences,
                       const int* __restrict__ num_targets,
                       int B, int S, int M,
                       float* __restrict__ sfT, int* __restrict__ b2s,
                       int* __restrict__ s2b, int* __restrict__ m2s,
                       float* __restrict__ denomq, int* __restrict__ counter) {
    __shared__ float red[4];
    int s = blockIdx.x, tid = threadIdx.x;
    float v = sents[(size_t)s * C + tid];
    float ssq = wave_reduce_sum(v * v);
    int lane = tid & 63, wave = tid >> 6;
    if (lane == 0) red[wave] = ssq;
    __syncthreads();
    float tot = red[0] + red[1] + red[2] + red[3];
    sfT[(size_t)tid * S + s] = v * (1.0f / fmaxf(sqrtf(tot), 1e-12f));

    if (blockIdx.x == 0) {
        if (tid < S) denomq[tid] = 0.f;
        if (tid == 0) *counter = 0;
        if (tid < B) {                       // b2s + s2b, one thread per batch
            int acc = 0;
            for (int i = 0; i < tid; ++i) acc += num_sentences[i];
            b2s[tid] = acc;
            int nsb = num_sentences[tid];
            for (int k = 0; k < nsb; ++k) s2b[acc + k] = tid;
        }
        if (tid >= 64 && tid < 64 + S) {     // m2s, one thread per sentence
            int si = tid - 64;
            int acc = 0;
            for (int i = 0; i < si; ++i) acc += num_targets[i];
            int nt = num_targets[si];
            for (int k = 0; k < nt; ++k) m2s[acc + k] = si;
        }
    }
}

// --- main: blocks [0,M) = topk/inter-video (latency-heavy, start first);
//     blocks [M, M+512) = inter-query GEMM+exp.
//     Q-part: 1 flat/thread, 32 sentences/block, sentence operand via
//     wave-uniform loads (SGPR), unroll 8 for 8 vf loads in flight.
//     (unroll 8 is the measured MLP optimum: 4 -> 383.7us, 8 -> 367.2us,
//      16 -> 380.7us — deeper unroll exceeds the SGPR budget for the
//      uniform sentence loads and lengthens the dependence chain.)
//     Last-finishing block computes the final loss. ----------------------
__global__ void __launch_bounds__(256)
k_main(const float* __restrict__ vf, const float* __restrict__ iou2d,
       const float* __restrict__ iou2ds, const int* __restrict__ num_sentences,
       const float* __restrict__ sfT, const int* __restrict__ b2s,
       const int* __restrict__ m2s,
       float* __restrict__ pos, float* __restrict__ negiv,
       float* __restrict__ denomq, int* __restrict__ counter,
       float* __restrict__ out, int S, int B, int M, int nq, int ntot) {
    __shared__ float red[4];
    __shared__ int   sidx[4];
    __shared__ float dw[4][SDIM];
    __shared__ int   bestflat;
    __shared__ int   amlast;
    __shared__ float tv[C];        // m-part only
    __shared__ float sc4[256];     // m-part only

    int bid = blockIdx.x, tid = threadIdx.x;
    int lane = tid & 63, wave = tid >> 6;

    if (bid >= M) {
        // ================= inter-query part =================
        int qb   = bid - M;              // [0, 512)
        int tile = qb & (QTILES - 1);    // 16 flat-tiles
        int rem  = qb >> 4;
        int b    = rem & 15;             // 16 videos
        int g    = rem >> 4;             // 2 sentence-groups of 32
        int sb = b2s[b];
        int ns = num_sentences[b];

        int flat = tile * QTILE + tid;   // this thread's proposal
        const float* vp = vf + (size_t)sb * C * NN + flat;
        // wave-uniform sentence pointer: float4 chunks of this group's 32 s
        const float4* sq = (const float4*)sfT + (size_t)g * 8;

        float acc[SG];                   // fully-unrolled -> stays in VGPRs
        #pragma unroll
        for (int s = 0; s < SG; ++s) acc[s] = 0.f;
        float ssq = 0.f;

        #pragma unroll 8
        for (int c = 0; c < C; ++c) {
            float v = vp[(size_t)c * NN];          // coalesced vector load
            ssq += v * v;
            const float4* sqc = sq + (size_t)c * (SDIM / 4);
            #pragma unroll
            for (int k = 0; k < SG / 4; ++k) {
                float4 q4 = sqc[k];                // uniform -> s_load
                acc[k * 4 + 0] += q4.x * v;
                acc[k * 4 + 1] += q4.y * v;
                acc[k * 4 + 2] += q4.z * v;
                acc[k * 4 + 3] += q4.w * v;
            }
        }

        int r = flat >> 6, cc = flat & 63;
        bool valid = (cc >= r);          // triu(mask2d)
        float scale = (1.0f / fmaxf(sqrtf(ssq), 1e-12f)) * T_INV;

        // own-batch positives are excluded from the denominator
        unsigned long long excl = 0ull;
        for (int i = 0; i < ns; ++i)
            if (iou2d[(size_t)(sb + i) * NN + flat] > NEG_IOU_TH)
                excl |= (1ull << (sb + i));
        if (!valid) excl = ~0ull;        // invalid flat contributes nothing

        unsigned mask32 = (unsigned)(excl >> (g * 32));
        #pragma unroll
        for (int i = 0; i < SG; ++i)
            acc[i] = ((mask32 >> i) & 1u) ? 0.f : expf(acc[i] * scale);

        // log-transpose reduce within each 32-lane half:
        // after this, lane l holds sum over its half's lanes of acc[l&31]
        #pragma unroll
        for (int off = 16; off >= 1; off >>= 1) {
            int bsel = lane & off;
            #pragma unroll
            for (int i = 0; i < off; ++i) {
                float keep = bsel ? acc[off + i] : acc[i];
                float send = bsel ? acc[i] : acc[off + i];
                acc[i] = keep + __shfl_xor(send, off, 64);
            }
        }
        float tot_s = acc[0] + __shfl_xor(acc[0], 32, 64);  // combine halves
        if (lane < 32) dw[wave][lane] = tot_s;   // s = g*32 + lane
        __syncthreads();
        if (tid < 32)
            atomicAdd(&denomq[g * 32 + tid],
                      dw[0][tid] + dw[1][tid] + dw[2][tid] + dw[3][tid]);
    } else {
        // ================= topk / inter-video part =================
        int m = bid;
        int s_m = m2s[m];

        float bv = -1e30f; int bi = NN;
        #pragma unroll
        for (int j = 0; j < NN / 256; ++j) {
            int flat = tid + j * 256;
            int rr = flat >> 6, cc = flat & 63;
            if (cc >= rr) {
                float val = iou2ds[(size_t)m * NN + flat];
                if (val > bv || (val == bv && flat < bi)) { bv = val; bi = flat; }
            }
        }
        #pragma unroll
        for (int off = 32; off > 0; off >>= 1) {
            float ov = __shfl_xor(bv, off, 64);
            int   oi = __shfl_xor(bi, off, 64);
            if (ov > bv || (ov == bv && oi < bi)) { bv = ov; bi = oi; }
        }
        if (lane == 0) { red[wave] = bv; sidx[wave] = bi; }
        __syncthreads();
        if (tid == 0) {
            float v0 = red[0]; int i0 = sidx[0];
            for (int w = 1; w < 4; ++w)
                if (red[w] > v0 || (red[w] == v0 && sidx[w] < i0)) { v0 = red[w]; i0 = sidx[w]; }
            bestflat = i0;
        }
        __syncthreads();
        int flat = bestflat;

        float v = vf[((size_t)s_m * C + tid) * NN + flat];
        float ssq = wave_reduce_sum(v * v);
        if (lane == 0) red[wave] = ssq;
        __syncthreads();
        float tot = red[0] + red[1] + red[2] + red[3];
        tv[tid] = v * (1.0f / fmaxf(sqrtf(tot), 1e-12f));
        __syncthreads();

        {
            int s = tid & 63, cg = tid >> 6;
            float d = 0.f;
            for (int j = 0; j < 64; ++j) {
                int c2 = cg * 64 + j;
                d += tv[c2] * sfT[(size_t)c2 * S + s];
            }
            sc4[cg * 64 + s] = d;
        }
        __syncthreads();
        if (tid < 64) {
            float d = sc4[tid] + sc4[64 + tid] + sc4[128 + tid] + sc4[192 + tid];
            if (tid == s_m) atomicExch(&pos[m], d);   // device-scope publish
            float e = (tid == s_m) ? 0.f : expf(d * T_INV);
            e = wave_reduce_sum(e);
            if (tid == 0) atomicExch(&negiv[m], e);   // device-scope publish
        }
    }

    // ---- completion tail: last block to finish computes the final loss ----
    __syncthreads();   // drains this block's outstanding memory ops
    if (tid == 0) {
        __threadfence();
        int old = atomicAdd(counter, 1);
        amlast = (old == ntot - 1) ? 1 : 0;
    }
    __syncthreads();
    if (!amlast) return;

    __threadfence();
    float val = 0.f;
    for (int m = tid; m < M; m += 256) {
        int s = m2s[m];
        float pl  = atomicAdd(&pos[m], 0.f) * T_INV;       // coherent reads
        float niv = atomicAdd(&negiv[m], 0.f);
        float dq  = atomicAdd(&denomq[s], 0.f);
        float pe = expf(pl);
        val += -(pl - logf(pe + niv)) + -(pl - logf(pe + dq));
    }
    val = wave_reduce_sum(val);
    if (lane == 0) dw[0][wave] = val;
    __syncthreads();
    if (tid == 0) out[0] = (dw[0][0] + dw[0][1] + dw[0][2] + dw[0][3]) / (float)M;
}

extern "C" void kernel_launch(void* const* d_in, const int* in_sizes, int n_in,
                              void* d_out, int out_size, void* d_ws, size_t ws_size,
                              hipStream_t stream) {
    const float* video_feats   = (const float*)d_in[0];
    const float* sents_feats   = (const float*)d_in[1];
    const float* iou2d         = (const float*)d_in[2];
    const float* iou2ds        = (const float*)d_in[3];
    const int*   num_sentences = (const int*)d_in[4];
    const int*   num_targets   = (const int*)d_in[5];
    // d_in[6] = mask2d: statically triu(ones(64,64)); computed as cc>=r in-kernel.

    const int S = in_sizes[2] / NN;   // 64
    const int B = in_sizes[4];        // 16
    const int M = in_sizes[3] / NN;   // 128

    float* sfT    = (float*)d_ws;              // C*S
    float* pos    = sfT + (size_t)C * 64;
    float* negiv  = pos + M;
    float* denomq = negiv + M;
    int*   b2s    = (int*)(denomq + S);
    int*   s2b    = b2s + B;
    int*   m2s    = s2b + S;
    int*   counter = m2s + M;

    const int nq   = QTILES * B * (SDIM / SG);   // 16*16*2 = 512 q-blocks
    const int ntot = M + nq;                     // 640

    k_prep<<<S, C, 0, stream>>>(sents_feats, num_sentences, num_targets,
                                B, S, M, sfT, b2s, s2b, m2s, denomq, counter);
    k_main<<<ntot, 256, 0, stream>>>(video_feats, iou2d, iou2ds, num_sentences,
                                     sfT, b2s, m2s, pos, negiv, denomq, counter,
                                     (float*)d_out, S, B, M, nq, ntot);
}